// Round 11
// baseline (413.926 us; speedup 1.0000x reference)
//
#include <hip/hip_runtime.h>

#define VOCAB 21
#define EMB 128
#define H1 64
#define H2 100
#define T1 500
#define TP 100
#define NB 1024
#define TBL_LD 260
#define LOG2E 1.44269504f

typedef __attribute__((ext_vector_type(8))) short bf16x8;
typedef __attribute__((ext_vector_type(4))) float f32x4;

__device__ __forceinline__ unsigned short f2bf(float x){
    union { float f; unsigned u; } v; v.f = x;
    return (unsigned short)((v.u + 0x8000u) >> 16);
}
// LDS-only barrier: do NOT drain vmcnt (global stores/loads stay in flight)
__device__ __forceinline__ void bar_lds(){
    asm volatile("s_waitcnt lgkmcnt(0)\n\ts_barrier" ::: "memory");
}
__device__ __forceinline__ float ex2(float x){ return __builtin_amdgcn_exp2f(x); }
__device__ __forceinline__ float rcp(float x){ return __builtin_amdgcn_rcpf(x); }
__device__ __forceinline__ float bperm(int bpa, float v){
    union { float f; int i; } a, r;
    a.f = v;
    r.i = __builtin_amdgcn_ds_bpermute(bpa, a.i);
    return r.f;
}

// ---------------------------------------------------------------------------
// Kernel 0: permuted xproj table, pre-scaled by log2(e).
// table[v][4*cell+gate] = LOG2E*(dot(W_ih1[gate*64+cell,:], emb[v,:]) + b_ih1 + b_hh1)
// ---------------------------------------------------------------------------
__global__ void k_table(const float* __restrict__ Wih, const float* __restrict__ emb,
                        const float* __restrict__ bih, const float* __restrict__ bhh,
                        float* __restrict__ table){
    const int p = threadIdx.x;
    const int v = blockIdx.x;
    const int orig = (p & 3) * H1 + (p >> 2);
    float s = bih[orig] + bhh[orig];
    if (v != 0){
        const float* w = Wih + orig * EMB;
        const float* e = emb + v * EMB;
        #pragma unroll 16
        for (int d = 0; d < EMB; ++d) s += w[d]*e[d];
    }
    table[v*TBL_LD + p] = s * LOG2E;
}

// ---------------------------------------------------------------------------
// Kernel 1: layer-1 LSTM. 4 rows/block, 256 blocks, 4 waves (R7 structure).
// Gate redistribute via ds_bpermute (intra-wave, no LDS round-trip, no glds):
// consumer lane l takes acc[u=l>>4] from lane s=16*((l>>2)&3)+(l&3).
// One lgkm-barrier per step for the cross-wave h broadcast.
// ---------------------------------------------------------------------------
__global__ __launch_bounds__(256, 1) void k_lstm1(
    const int* __restrict__ xidx, const float* __restrict__ Whh,
    const float* __restrict__ tbl_g, float* __restrict__ x2){
  __shared__ __align__(16) float table[VOCAB*TBL_LD];    // 21840 B
  __shared__ __align__(16) unsigned short hbuf[2][16*64];// 4096 B (XOR-swizzled)
  __shared__ int idxs[4*T1];                             // 8000 B

  const int tid = threadIdx.x;
  const int w = tid >> 6, l = tid & 63;
  const int b0 = blockIdx.x * 4;
  const int n = l & 15, kg = l >> 4;

  for (int i = tid; i < VOCAB*TBL_LD; i += 256) table[i] = tbl_g[i];
  for (int i = tid; i < 4*T1; i += 256){
      int r = i / T1, t = i - r*T1;
      idxs[i] = xidx[(b0 + r)*T1 + t];
  }
  { unsigned short* hz = (unsigned short*)hbuf;
    for (int i = tid; i < 2048; i += 256) hz[i] = 0; }

  // A fragments (permuted Whh * LOG2E): tiles gt=4w+u
  bf16x8 af[4][2];
  #pragma unroll
  for (int u = 0; u < 4; ++u){
      const int p = 16*(4*w + u) + n;
      const int orig = (p & 3)*H1 + (p >> 2);
      #pragma unroll
      for (int c = 0; c < 2; ++c){
          const float* src = Whh + orig*H1 + c*32 + kg*8;
          bf16x8 f;
          #pragma unroll
          for (int j = 0; j < 8; ++j) f[j] = (short)f2bf(src[j] * LOG2E);
          af[u][c] = f;
      }
  }

  char* hb = (char*)hbuf;
  const int swz = (n & 7) << 4;
  const int rb0 = (n*128 + 16*kg) ^ swz;
  const int rb1 = (n*128 + 64 + 16*kg) ^ swz;
  // consumer: lane l -> cell = 16w + (l>>2), row r_c = l&3 (all 64 real)
  const int cell = 16*w + (l >> 2);
  const int r_c  = l & 3;
  const int u0   = l >> 4;
  const int bpa  = 4*(16*((l >> 2) & 3) + (l & 3));   // source lane * 4
  const int wbh  = (r_c*128 + 2*cell) ^ (r_c << 4);
  const float twoL = 2.0f * LOG2E;

  float cc = 0.f, pm = -1e30f;
  __syncthreads();

  int vv = idxs[r_c*T1];
  f32x4 tq = *(const f32x4*)&table[vv*TBL_LD + 4*cell];
  int vnext = idxs[r_c*T1 + 1];
  const f32x4 z4 = {0.f, 0.f, 0.f, 0.f};

  int rp = 0, tm = 0, tp = 0;
  for (int t = 0; t < T1; ++t){
      bf16x8 bf0 = *(const bf16x8*)(hb + rp + rb0);
      bf16x8 bf1 = *(const bf16x8*)(hb + rp + rb1);
      f32x4 acc[4];
      #pragma unroll
      for (int u = 0; u < 4; ++u){
          f32x4 a = __builtin_amdgcn_mfma_f32_16x16x32_bf16(af[u][0], bf0, z4, 0,0,0);
          f32x4 b = __builtin_amdgcn_mfma_f32_16x16x32_bf16(af[u][1], bf1, z4, 0,0,0);
          acc[u] = a + b;
      }
      // intra-wave redistribute: 16 bpermutes + 12 selects
      f32x4 r0, r1, r2, r3;
      #pragma unroll
      for (int j = 0; j < 4; ++j){
          r0[j] = bperm(bpa, acc[0][j]);
          r1[j] = bperm(bpa, acc[1][j]);
          r2[j] = bperm(bpa, acc[2][j]);
          r3[j] = bperm(bpa, acc[3][j]);
      }
      f32x4 qa = (u0 & 1) ? r1 : r0;
      f32x4 qb = (u0 & 1) ? r3 : r2;
      f32x4 q  = (u0 & 2) ? qb : qa;
      // off-chain prefetches for t+1
      f32x4 tvn = *(const f32x4*)&table[vnext*TBL_LD + 4*cell];
      int vn2 = idxs[r_c*T1 + ((t + 2 < T1) ? (t + 2) : 0)];
      float gi = q[0] + tq[0];
      float gf = q[1] + tq[1];
      float gg = q[2] + tq[2];
      float go = q[3] + tq[3];
      float si = rcp(1.f + ex2(-gi));
      float sf = rcp(1.f + ex2(-gf));
      float so = rcp(1.f + ex2(-go));
      float tg = 1.f - 2.f*rcp(1.f + ex2(gg + gg));
      cc = sf*cc + si*tg;
      float th = 1.f - 2.f*rcp(1.f + ex2(twoL*cc));
      float h = so*th;
      const int wp = rp ^ 2048;
      *(unsigned short*)(hb + wp + wbh) = f2bf(h);
      pm = fmaxf(pm, h);
      if (++tm == 5){
          x2[(b0 + r_c)*(TP*H1) + tp*H1 + cell] = pm;   // async store
          pm = -1e30f; tm = 0; ++tp;
      }
      tq = tvn; vnext = vn2;
      rp = wp;
      bar_lds();
  }
}

// ---------------------------------------------------------------------------
// Kernel 2: layer-2 LSTM. 4 rows/block, 256 blocks, 8 waves; 26 tiles split
// 4,4,3,3,3,3,3,3. Gate redistribute via ds_bpermute (wave-local, nt-guarded);
// split-acc MFMA; issue-early x staging on waves 6,7.
// ---------------------------------------------------------------------------
__global__ __launch_bounds__(512, 1) void k_lstm2(
    const float* __restrict__ x2, const float* __restrict__ Wih,
    const float* __restrict__ Whh, const float* __restrict__ bih,
    const float* __restrict__ bhh, const float* __restrict__ fcw,
    const float* __restrict__ fcb, float* __restrict__ out){
  __shared__ __align__(16) unsigned short blds[2][16*192];   // 12288 B
  __shared__ float fcred[8][4];

  const int tid = threadIdx.x;
  const int w = tid >> 6, l = tid & 63;
  const int b0 = blockIdx.x * 4;
  const int n = l & 15, kg = l >> 4;
  const int tlo = (w < 2) ? 4*w : 8 + 3*(w - 2);
  const int nt  = (w < 2) ? 4 : 3;

  { unsigned* bz0 = (unsigned*)blds;
    for (int i = tid; i < 3072; i += 512) bz0[i] = 0; }

  // A fragments: [W_ih2 | W_hh2] permuted * LOG2E, zero-padded
  bf16x8 af[4][6];
  #pragma unroll
  for (int u = 0; u < 4; ++u){
      if (u < nt){
          const int p = 16*(tlo + u) + n;
          const int cell_ = p >> 2, gate = p & 3;
          #pragma unroll
          for (int c = 0; c < 6; ++c){
              bf16x8 f;
              #pragma unroll
              for (int jj = 0; jj < 8; ++jj){
                  int k = c*32 + kg*8 + jj;
                  float vv = 0.f;
                  if (cell_ < H2){
                      if (k < 64)           vv = Wih[(gate*H2 + cell_)*H1 + k];
                      else if (k < 64 + H2) vv = Whh[(gate*H2 + cell_)*H2 + (k - 64)];
                  }
                  f[jj] = (short)f2bf(vv * LOG2E);
              }
              af[u][c] = f;
          }
      }
  }

  // bias C-init quads (producer layout), * LOG2E
  f32x4 bz[4];
  #pragma unroll
  for (int u = 0; u < 4; ++u){
      const int cu = 4*(tlo + u) + kg;
      f32x4 b = {0.f,0.f,0.f,0.f};
      if (u < nt && cu < H2){
          #pragma unroll
          for (int g = 0; g < 4; ++g) b[g] = (bih[g*H2 + cu] + bhh[g*H2 + cu]) * LOG2E;
      }
      bz[u] = b;
  }

  // consumer: lane l -> cell = 4*tlo + (l>>2), row = l&3
  const bool act = (l >> 2) < 4*nt;
  const int cellc = 4*tlo + (l >> 2);
  const int r_c = l & 3;
  const int u0  = l >> 4;
  const int bpa = 4*(16*((l >> 2) & 3) + (l & 3));
  const float fwv = (act && cellc < H2) ? fcw[cellc] : 0.f;
  const float twoL = 2.0f * LOG2E;

  char* bb = (char*)blds;
  const int swz = (n & 7) << 4;
  int rb[6];
  #pragma unroll
  for (int c = 0; c < 6; ++c) rb[c] = (n*384 + 64*c + 16*kg) ^ swz;
  const int wbh = (r_c*384 + 2*(64 + cellc)) ^ (r_c << 4);

  // x-staging role: waves 6,7 (tid>=384): row xr, cells 2*xc, 2*xc+1
  const int xr = (tid >> 5) & 3, xc = tid & 31;
  const int xwb = (xr*384 + 4*xc) ^ (xr << 4);
  if (tid >= 384){
      float2 v = *(const float2*)&x2[(b0 + xr)*(TP*H1) + 2*xc];
      unsigned pk = (unsigned)f2bf(v.x) | ((unsigned)f2bf(v.y) << 16);
      *(unsigned*)(bb + xwb) = pk;
  }
  float cc = 0.f, hv = 0.f;
  __syncthreads();

  int rp = 0;
  for (int t = 0; t < TP; ++t){
      float2 xn = {0.f, 0.f};
      if (tid >= 384 && t + 1 < TP)              // T14 issue-early
          xn = *(const float2*)&x2[(b0 + xr)*(TP*H1) + (t+1)*H1 + 2*xc];
      bf16x8 bf[6];
      #pragma unroll
      for (int c = 0; c < 6; ++c) bf[c] = *(const bf16x8*)(bb + rp + rb[c]);
      f32x4 acc[4];
      #pragma unroll
      for (int u = 0; u < 4; ++u){
          if (u < nt){
              f32x4 za = __builtin_amdgcn_mfma_f32_16x16x32_bf16(af[u][0], bf[0], bz[u], 0,0,0);
              f32x4 zb = __builtin_amdgcn_mfma_f32_16x16x32_bf16(af[u][1], bf[1], (f32x4){0.f,0.f,0.f,0.f}, 0,0,0);
              za = __builtin_amdgcn_mfma_f32_16x16x32_bf16(af[u][2], bf[2], za, 0,0,0);
              zb = __builtin_amdgcn_mfma_f32_16x16x32_bf16(af[u][3], bf[3], zb, 0,0,0);
              za = __builtin_amdgcn_mfma_f32_16x16x32_bf16(af[u][4], bf[4], za, 0,0,0);
              zb = __builtin_amdgcn_mfma_f32_16x16x32_bf16(af[u][5], bf[5], zb, 0,0,0);
              acc[u] = za + zb;
          }
      }
      // intra-wave redistribute via bpermute (nt-guarded)
      f32x4 r0, r1, r2, r3;
      #pragma unroll
      for (int j = 0; j < 4; ++j){
          r0[j] = bperm(bpa, acc[0][j]);
          r1[j] = bperm(bpa, acc[1][j]);
          r2[j] = bperm(bpa, acc[2][j]);
      }
      if (nt == 4){
          #pragma unroll
          for (int j = 0; j < 4; ++j) r3[j] = bperm(bpa, acc[3][j]);
      } else {
          r3 = r2;
      }
      f32x4 qa = (u0 & 1) ? r1 : r0;
      f32x4 qb = (u0 & 1) ? r3 : r2;
      f32x4 q  = (u0 & 2) ? qb : qa;
      const int wp = rp ^ 6144;
      float si = rcp(1.f + ex2(-q[0]));
      float sf = rcp(1.f + ex2(-q[1]));
      float so = rcp(1.f + ex2(-q[3]));
      float tg = 1.f - 2.f*rcp(1.f + ex2(q[2] + q[2]));
      cc = sf*cc + si*tg;
      float th = 1.f - 2.f*rcp(1.f + ex2(twoL*cc));
      hv = so*th;
      if (act) *(unsigned short*)(bb + wp + wbh) = f2bf(hv);
      if (tid >= 384 && t + 1 < TP){             // write-late
          unsigned pk = (unsigned)f2bf(xn.x) | ((unsigned)f2bf(xn.y) << 16);
          *(unsigned*)(bb + wp + xwb) = pk;
      }
      rp = wp;
      bar_lds();
  }

  // FC + sigmoid: p=0 on junk lanes, reduce cells then waves
  float p = (act && cellc < H2) ? hv * fwv : 0.f;
  p += __shfl_xor(p, 4);
  p += __shfl_xor(p, 8);
  p += __shfl_xor(p, 16);
  p += __shfl_xor(p, 32);
  if (l < 4) fcred[w][l] = p;
  __syncthreads();
  if (tid < 4){
      float s = 0.f;
      #pragma unroll
      for (int ww = 0; ww < 8; ++ww) s += fcred[ww][tid];
      s += fcb[0];
      out[b0 + tid] = rcp(1.f + ex2(-s * LOG2E));
  }
}

// ---------------------------------------------------------------------------
extern "C" void kernel_launch(void* const* d_in, const int* in_sizes, int n_in,
                              void* d_out, int out_size, void* d_ws, size_t ws_size,
                              hipStream_t stream) {
    const int*   x_idx = (const int*)  d_in[0];
    const float* emb   = (const float*)d_in[1];
    const float* Wih1  = (const float*)d_in[2];
    const float* Whh1  = (const float*)d_in[3];
    const float* bih1  = (const float*)d_in[4];
    const float* bhh1  = (const float*)d_in[5];
    const float* Wih2  = (const float*)d_in[6];
    const float* Whh2  = (const float*)d_in[7];
    const float* bih2  = (const float*)d_in[8];
    const float* bhh2  = (const float*)d_in[9];
    const float* fcw   = (const float*)d_in[10];
    const float* fcb   = (const float*)d_in[11];
    float* out = (float*)d_out;

    float* table = (float*)d_ws;                       // 21*260*4 = 21840 B
    float* x2    = (float*)((char*)d_ws + 32768);      // 1024*100*64*4 = 26.2 MB

    k_table<<<VOCAB, 256, 0, stream>>>(Wih1, emb, bih1, bhh1, table);
    k_lstm1<<<NB / 4, 256, 0, stream>>>(x_idx, Whh1, table, x2);
    k_lstm2<<<NB / 4, 512, 0, stream>>>(x2, Wih2, Whh2, bih2, bhh2, fcw, fcb, out);
}

// Round 12
// 320.767 us; speedup vs baseline: 1.2904x; 1.2904x over previous
//
#include <hip/hip_runtime.h>

#define VOCAB 21
#define EMB 128
#define H1 64
#define H2 100
#define T1 500
#define TP 100
#define NB 1024
#define TBL_LD 260
#define LOG2E 1.44269504f

typedef __attribute__((ext_vector_type(8))) short bf16x8;
typedef __attribute__((ext_vector_type(4))) float f32x4;

__device__ __forceinline__ unsigned short f2bf(float x){
    union { float f; unsigned u; } v; v.f = x;
    return (unsigned short)((v.u + 0x8000u) >> 16);
}
// LDS-only barrier: do NOT drain vmcnt (global stores/loads stay in flight)
__device__ __forceinline__ void bar_lds(){
    asm volatile("s_waitcnt lgkmcnt(0)\n\ts_barrier" ::: "memory");
}
__device__ __forceinline__ void wait_lds(){
    asm volatile("s_waitcnt lgkmcnt(0)" ::: "memory");
}
__device__ __forceinline__ float ex2(float x){ return __builtin_amdgcn_exp2f(x); }
__device__ __forceinline__ float rcp(float x){ return __builtin_amdgcn_rcpf(x); }

// ---------------------------------------------------------------------------
// Kernel 0: permuted xproj table, pre-scaled by log2(e).
// table[v][4*cell+gate] = LOG2E*(dot(W_ih1[gate*64+cell,:], emb[v,:]) + b_ih1 + b_hh1)
// ---------------------------------------------------------------------------
__global__ void k_table(const float* __restrict__ Wih, const float* __restrict__ emb,
                        const float* __restrict__ bih, const float* __restrict__ bhh,
                        float* __restrict__ table){
    const int p = threadIdx.x;
    const int v = blockIdx.x;
    const int orig = (p & 3) * H1 + (p >> 2);
    float s = bih[orig] + bhh[orig];
    if (v != 0){
        const float* w = Wih + orig * EMB;
        const float* e = emb + v * EMB;
        #pragma unroll 16
        for (int d = 0; d < EMB; ++d) s += w[d]*e[d];
    }
    table[v*TBL_LD + p] = s * LOG2E;
}

// ---------------------------------------------------------------------------
// Kernel 1: layer-1 LSTM. 16 rows/block, 64 blocks, 16 waves (1 tile/wave).
// ZERO junk, ZERO redistribute: lane l of wave gt holds the complete
// (i,f,g,o) quad for (cell = 4*gt + (l>>4), row = l&15) straight from the
// MFMA acc (p = 4*cell+gate permutation). xproj quad = MFMA C-init.
// 4 waves/SIMD hide latency. One lgkm-barrier per step.
// ---------------------------------------------------------------------------
__global__ __launch_bounds__(1024, 1) void k_lstm1(
    const int* __restrict__ xidx, const float* __restrict__ Whh,
    const float* __restrict__ tbl_g, float* __restrict__ x2){
  __shared__ __align__(16) float table[VOCAB*TBL_LD];      // 21840 B
  __shared__ __align__(16) unsigned short hbuf[2][16*64];  // 4096 B (XOR-swizzled)
  __shared__ int idxs[16*T1];                              // 32000 B

  const int tid = threadIdx.x;
  const int gt = tid >> 6, l = tid & 63;     // wave == tile
  const int b0 = blockIdx.x * 16;
  const int row = l & 15, kg = l >> 4;

  for (int i = tid; i < VOCAB*TBL_LD; i += 1024) table[i] = tbl_g[i];
  for (int i = tid; i < 16*T1; i += 1024){
      int r = i / T1, t = i - r*T1;
      idxs[i] = xidx[(b0 + r)*T1 + t];
  }
  { unsigned short* hz = (unsigned short*)hbuf;
    for (int i = tid; i < 2048; i += 1024) hz[i] = 0; }

  // A fragments (permuted Whh * LOG2E): single tile gt, 8 VGPRs
  bf16x8 af0, af1;
  {
      const int p = 16*gt + row;
      const int orig = (p & 3)*H1 + (p >> 2);
      bf16x8 f;
      const float* s0 = Whh + orig*H1 + kg*8;
      #pragma unroll
      for (int j = 0; j < 8; ++j) f[j] = (short)f2bf(s0[j] * LOG2E);
      af0 = f;
      const float* s1 = Whh + orig*H1 + 32 + kg*8;
      #pragma unroll
      for (int j = 0; j < 8; ++j) f[j] = (short)f2bf(s1[j] * LOG2E);
      af1 = f;
  }

  char* hb = (char*)hbuf;
  const int swz = (row & 7) << 4;
  const int rb0 = (row*128 + 16*kg) ^ swz;
  const int rb1 = (row*128 + 64 + 16*kg) ^ swz;
  const int cell = 4*gt + kg;                       // this lane's cell
  const int wbh  = (row*128 + 2*cell) ^ swz;
  const float twoL = 2.0f * LOG2E;

  float cc = 0.f, pm = -1e30f;
  __syncthreads();

  int vv = idxs[row*T1];
  f32x4 tq = *(const f32x4*)&table[vv*TBL_LD + 4*cell];
  int vnext = idxs[row*T1 + 1];

  int rp = 0, tm = 0, tp = 0;
  for (int t = 0; t < T1; ++t){
      bf16x8 bf0 = *(const bf16x8*)(hb + rp + rb0);
      bf16x8 bf1 = *(const bf16x8*)(hb + rp + rb1);
      f32x4 a = __builtin_amdgcn_mfma_f32_16x16x32_bf16(af0, bf0, tq, 0,0,0);
      f32x4 z = __builtin_amdgcn_mfma_f32_16x16x32_bf16(af1, bf1, a, 0,0,0);
      // off-chain prefetches for t+1
      f32x4 tqn = *(const f32x4*)&table[vnext*TBL_LD + 4*cell];
      int vn2 = idxs[row*T1 + ((t + 2 < T1) ? (t + 2) : 0)];
      // gates: z = (i,f,g,o) for (cell,row), pre-scaled by log2e
      float si = rcp(1.f + ex2(-z[0]));
      float sf = rcp(1.f + ex2(-z[1]));
      float so = rcp(1.f + ex2(-z[3]));
      float tg = 1.f - 2.f*rcp(1.f + ex2(z[2] + z[2]));
      cc = sf*cc + si*tg;
      float th = 1.f - 2.f*rcp(1.f + ex2(twoL*cc));
      float h = so*th;
      const int wp = rp ^ 2048;
      *(unsigned short*)(hb + wp + wbh) = f2bf(h);
      pm = fmaxf(pm, h);
      if (++tm == 5){
          x2[(b0 + row)*(TP*H1) + tp*H1 + cell] = pm;   // async store
          pm = -1e30f; tm = 0; ++tp;
      }
      tq = tqn; vnext = vn2;
      rp = wp;
      bar_lds();
  }
}

// ---------------------------------------------------------------------------
// Kernel 2: layer-2 LSTM — R7/R10 known-good version. 4 rows/block, 256
// blocks, 8 waves; 26 tiles split 4,4,3,3,3,3,3,3. Wave-local redistribute
// into gl2[cell][row]; <=1 real update/lane. Split accumulators.
// ---------------------------------------------------------------------------
__global__ __launch_bounds__(512, 1) void k_lstm2(
    const float* __restrict__ x2, const float* __restrict__ Wih,
    const float* __restrict__ Whh, const float* __restrict__ bih,
    const float* __restrict__ bhh, const float* __restrict__ fcw,
    const float* __restrict__ fcb, float* __restrict__ out){
  __shared__ __align__(16) unsigned short blds[2][16*192];   // 12288 B
  __shared__ __align__(16) f32x4 gl2[108*4];                 // 6912 B [cell][row]
  __shared__ float fcred[8][4];

  const int tid = threadIdx.x;
  const int w = tid >> 6, l = tid & 63;
  const int b0 = blockIdx.x * 4;
  const int n = l & 15, kg = l >> 4;
  const int tlo = (w < 2) ? 4*w : 8 + 3*(w - 2);
  const int nt  = (w < 2) ? 4 : 3;

  { unsigned* bz0 = (unsigned*)blds;
    for (int i = tid; i < 3072; i += 512) bz0[i] = 0; }
  { float* gz = (float*)gl2;
    for (int i = tid; i < 432*4; i += 512) gz[i] = 0.f; }

  // A fragments: [W_ih2 | W_hh2] permuted * LOG2E, zero-padded
  bf16x8 af[4][6];
  #pragma unroll
  for (int u = 0; u < 4; ++u){
      if (u < nt){
          const int p = 16*(tlo + u) + n;
          const int cell_ = p >> 2, gate = p & 3;
          #pragma unroll
          for (int c = 0; c < 6; ++c){
              bf16x8 f;
              #pragma unroll
              for (int jj = 0; jj < 8; ++jj){
                  int k = c*32 + kg*8 + jj;
                  float vv = 0.f;
                  if (cell_ < H2){
                      if (k < 64)           vv = Wih[(gate*H2 + cell_)*H1 + k];
                      else if (k < 64 + H2) vv = Whh[(gate*H2 + cell_)*H2 + (k - 64)];
                  }
                  f[jj] = (short)f2bf(vv * LOG2E);
              }
              af[u][c] = f;
          }
      }
  }

  // bias C-init quads (producer layout), * LOG2E
  f32x4 bz[4];
  #pragma unroll
  for (int u = 0; u < 4; ++u){
      const int cu = 4*(tlo + u) + kg;
      f32x4 b = {0.f,0.f,0.f,0.f};
      if (u < nt && cu < H2){
          #pragma unroll
          for (int g = 0; g < 4; ++g) b[g] = (bih[g*H2 + cu] + bhh[g*H2 + cu]) * LOG2E;
      }
      bz[u] = b;
  }

  // consumer: lane l -> cell = 4*tlo + (l>>2), row = l&3; active if in-range
  const bool act = (l >> 2) < 4*nt;
  const int cellc = 4*tlo + (l >> 2);
  const int r_c = l & 3;
  const float fwv = (act && cellc < H2) ? fcw[cellc] : 0.f;
  const float twoL = 2.0f * LOG2E;

  char* bb = (char*)blds;
  char* gb = (char*)gl2;
  const int swz = (n & 7) << 4;
  int rb[6];
  #pragma unroll
  for (int c = 0; c < 6; ++c) rb[c] = (n*384 + 64*c + 16*kg) ^ swz;
  const int wbh = (r_c*384 + 2*(64 + cellc)) ^ (r_c << 4);

  // x-staging role: waves 6,7 (tid>=384): row xr, cells 2*xc, 2*xc+1
  const int xr = (tid >> 5) & 3, xc = tid & 31;
  const int xwb = (xr*384 + 4*xc) ^ (xr << 4);
  if (tid >= 384){
      float2 v = *(const float2*)&x2[(b0 + xr)*(TP*H1) + 2*xc];
      unsigned pk = (unsigned)f2bf(v.x) | ((unsigned)f2bf(v.y) << 16);
      *(unsigned*)(bb + xwb) = pk;
  }
  float cc = 0.f, hv = 0.f;
  __syncthreads();

  int rp = 0;
  for (int t = 0; t < TP; ++t){
      float2 xn = {0.f, 0.f};
      if (tid >= 384 && t + 1 < TP)              // T14 issue-early
          xn = *(const float2*)&x2[(b0 + xr)*(TP*H1) + (t+1)*H1 + 2*xc];
      bf16x8 bf[6];
      #pragma unroll
      for (int c = 0; c < 6; ++c) bf[c] = *(const bf16x8*)(bb + rp + rb[c]);
      #pragma unroll
      for (int u = 0; u < 4; ++u){
          if (u < nt){
              f32x4 za = __builtin_amdgcn_mfma_f32_16x16x32_bf16(af[u][0], bf[0], bz[u], 0,0,0);
              f32x4 zb = __builtin_amdgcn_mfma_f32_16x16x32_bf16(af[u][1], bf[1], (f32x4){0.f,0.f,0.f,0.f}, 0,0,0);
              za = __builtin_amdgcn_mfma_f32_16x16x32_bf16(af[u][2], bf[2], za, 0,0,0);
              zb = __builtin_amdgcn_mfma_f32_16x16x32_bf16(af[u][3], bf[3], zb, 0,0,0);
              za = __builtin_amdgcn_mfma_f32_16x16x32_bf16(af[u][4], bf[4], za, 0,0,0);
              zb = __builtin_amdgcn_mfma_f32_16x16x32_bf16(af[u][5], bf[5], zb, 0,0,0);
              f32x4 z = za + zb;
              if (n < 4)                          // cell 4*(tlo+u)+kg, row n
                  *(f32x4*)(gb + 256*(tlo + u) + 64*kg + 16*n) = z;
          }
      }
      wait_lds();
      const int wp = rp ^ 6144;
      if (act){
          f32x4 q = *(const f32x4*)(gb + 256*tlo + 16*l);
          float si = rcp(1.f + ex2(-q[0]));
          float sf = rcp(1.f + ex2(-q[1]));
          float so = rcp(1.f + ex2(-q[3]));
          float tg = 1.f - 2.f*rcp(1.f + ex2(q[2] + q[2]));
          cc = sf*cc + si*tg;
          float th = 1.f - 2.f*rcp(1.f + ex2(twoL*cc));
          hv = so*th;
          *(unsigned short*)(bb + wp + wbh) = f2bf(hv);
      }
      if (tid >= 384 && t + 1 < TP){             // write-late
          unsigned pk = (unsigned)f2bf(xn.x) | ((unsigned)f2bf(xn.y) << 16);
          *(unsigned*)(bb + wp + xwb) = pk;
      }
      rp = wp;
      bar_lds();
  }

  // FC + sigmoid: p=0 on junk lanes, reduce cells then waves
  float p = (act && cellc < H2) ? hv * fwv : 0.f;
  p += __shfl_xor(p, 4);
  p += __shfl_xor(p, 8);
  p += __shfl_xor(p, 16);
  p += __shfl_xor(p, 32);
  if (l < 4) fcred[w][l] = p;
  __syncthreads();
  if (tid < 4){
      float s = 0.f;
      #pragma unroll
      for (int ww = 0; ww < 8; ++ww) s += fcred[ww][tid];
      s += fcb[0];
      out[b0 + tid] = rcp(1.f + ex2(-s * LOG2E));
  }
}

// ---------------------------------------------------------------------------
extern "C" void kernel_launch(void* const* d_in, const int* in_sizes, int n_in,
                              void* d_out, int out_size, void* d_ws, size_t ws_size,
                              hipStream_t stream) {
    const int*   x_idx = (const int*)  d_in[0];
    const float* emb   = (const float*)d_in[1];
    const float* Wih1  = (const float*)d_in[2];
    const float* Whh1  = (const float*)d_in[3];
    const float* bih1  = (const float*)d_in[4];
    const float* bhh1  = (const float*)d_in[5];
    const float* Wih2  = (const float*)d_in[6];
    const float* Whh2  = (const float*)d_in[7];
    const float* bih2  = (const float*)d_in[8];
    const float* bhh2  = (const float*)d_in[9];
    const float* fcw   = (const float*)d_in[10];
    const float* fcb   = (const float*)d_in[11];
    float* out = (float*)d_out;

    float* table = (float*)d_ws;                       // 21*260*4 = 21840 B
    float* x2    = (float*)((char*)d_ws + 32768);      // 1024*100*64*4 = 26.2 MB

    k_table<<<VOCAB, 256, 0, stream>>>(Wih1, emb, bih1, bhh1, table);
    k_lstm1<<<NB / 16, 1024, 0, stream>>>(x_idx, Whh1, table, x2);
    k_lstm2<<<NB / 4, 512, 0, stream>>>(x2, Wih2, Whh2, bih2, bhh2, fcw, fcb, out);
}

// Round 13
// 305.747 us; speedup vs baseline: 1.3538x; 1.0491x over previous
//
#include <hip/hip_runtime.h>

#define VOCAB 21
#define EMB 128
#define H1 64
#define H2 100
#define T1 500
#define TP 100
#define NB 1024
#define TBL_LD 260
#define LOG2E 1.44269504f

typedef __attribute__((ext_vector_type(8))) short bf16x8;
typedef __attribute__((ext_vector_type(4))) float f32x4;

__device__ __forceinline__ unsigned short f2bf(float x){
    union { float f; unsigned u; } v; v.f = x;
    return (unsigned short)((v.u + 0x8000u) >> 16);
}
// LDS-only barrier: do NOT drain vmcnt (global stores/loads stay in flight)
__device__ __forceinline__ void bar_lds(){
    asm volatile("s_waitcnt lgkmcnt(0)\n\ts_barrier" ::: "memory");
}
__device__ __forceinline__ void wait_lds(){
    asm volatile("s_waitcnt lgkmcnt(0)" ::: "memory");
}
__device__ __forceinline__ float ex2(float x){ return __builtin_amdgcn_exp2f(x); }
__device__ __forceinline__ float rcp(float x){ return __builtin_amdgcn_rcpf(x); }

// ---------------------------------------------------------------------------
// Kernel 0: permuted xproj table, pre-scaled by log2(e).
// table[v][4*cell+gate] = LOG2E*(dot(W_ih1[gate*64+cell,:], emb[v,:]) + b_ih1 + b_hh1)
// ---------------------------------------------------------------------------
__global__ void k_table(const float* __restrict__ Wih, const float* __restrict__ emb,
                        const float* __restrict__ bih, const float* __restrict__ bhh,
                        float* __restrict__ table){
    const int p = threadIdx.x;
    const int v = blockIdx.x;
    const int orig = (p & 3) * H1 + (p >> 2);
    float s = bih[orig] + bhh[orig];
    if (v != 0){
        const float* w = Wih + orig * EMB;
        const float* e = emb + v * EMB;
        #pragma unroll 16
        for (int d = 0; d < EMB; ++d) s += w[d]*e[d];
    }
    table[v*TBL_LD + p] = s * LOG2E;
}

// ---------------------------------------------------------------------------
// Kernel 1: layer-1 LSTM (R12, unchanged core). 16 rows/block, 64 blocks,
// 16 waves (1 tile/wave). Zero junk, zero redistribute: lane l of wave gt
// holds (i,f,g,o) of (cell = 4*gt + (l>>4), row = l&15) straight from the
// MFMA acc. xproj quad = MFMA C-init. Output x2 now stored as bf16.
// ---------------------------------------------------------------------------
__global__ __launch_bounds__(1024, 1) void k_lstm1(
    const int* __restrict__ xidx, const float* __restrict__ Whh,
    const float* __restrict__ tbl_g, unsigned short* __restrict__ x2b){
  __shared__ __align__(16) float table[VOCAB*TBL_LD];      // 21840 B
  __shared__ __align__(16) unsigned short hbuf[2][16*64];  // 4096 B (XOR-swizzled)
  __shared__ int idxs[16*T1];                              // 32000 B

  const int tid = threadIdx.x;
  const int gt = tid >> 6, l = tid & 63;     // wave == tile
  const int b0 = blockIdx.x * 16;
  const int row = l & 15, kg = l >> 4;

  for (int i = tid; i < VOCAB*TBL_LD; i += 1024) table[i] = tbl_g[i];
  for (int i = tid; i < 16*T1; i += 1024){
      int r = i / T1, t = i - r*T1;
      idxs[i] = xidx[(b0 + r)*T1 + t];
  }
  { unsigned short* hz = (unsigned short*)hbuf;
    for (int i = tid; i < 2048; i += 1024) hz[i] = 0; }

  // A fragments (permuted Whh * LOG2E): single tile gt, 8 VGPRs
  bf16x8 af0, af1;
  {
      const int p = 16*gt + row;
      const int orig = (p & 3)*H1 + (p >> 2);
      bf16x8 f;
      const float* s0 = Whh + orig*H1 + kg*8;
      #pragma unroll
      for (int j = 0; j < 8; ++j) f[j] = (short)f2bf(s0[j] * LOG2E);
      af0 = f;
      const float* s1 = Whh + orig*H1 + 32 + kg*8;
      #pragma unroll
      for (int j = 0; j < 8; ++j) f[j] = (short)f2bf(s1[j] * LOG2E);
      af1 = f;
  }

  char* hb = (char*)hbuf;
  const int swz = (row & 7) << 4;
  const int rb0 = (row*128 + 16*kg) ^ swz;
  const int rb1 = (row*128 + 64 + 16*kg) ^ swz;
  const int cell = 4*gt + kg;                       // this lane's cell
  const int wbh  = (row*128 + 2*cell) ^ swz;
  const float twoL = 2.0f * LOG2E;

  float cc = 0.f, pm = -1e30f;
  __syncthreads();

  int vv = idxs[row*T1];
  f32x4 tq = *(const f32x4*)&table[vv*TBL_LD + 4*cell];
  int vnext = idxs[row*T1 + 1];

  int rp = 0, tm = 0, tp = 0;
  for (int t = 0; t < T1; ++t){
      bf16x8 bf0 = *(const bf16x8*)(hb + rp + rb0);
      bf16x8 bf1 = *(const bf16x8*)(hb + rp + rb1);
      f32x4 a = __builtin_amdgcn_mfma_f32_16x16x32_bf16(af0, bf0, tq, 0,0,0);
      f32x4 z = __builtin_amdgcn_mfma_f32_16x16x32_bf16(af1, bf1, a, 0,0,0);
      // off-chain prefetches for t+1
      f32x4 tqn = *(const f32x4*)&table[vnext*TBL_LD + 4*cell];
      int vn2 = idxs[row*T1 + ((t + 2 < T1) ? (t + 2) : 0)];
      // gates: z = (i,f,g,o) for (cell,row), pre-scaled by log2e
      float si = rcp(1.f + ex2(-z[0]));
      float sf = rcp(1.f + ex2(-z[1]));
      float so = rcp(1.f + ex2(-z[3]));
      float tg = 1.f - 2.f*rcp(1.f + ex2(z[2] + z[2]));
      cc = sf*cc + si*tg;
      float th = 1.f - 2.f*rcp(1.f + ex2(twoL*cc));
      float h = so*th;
      const int wp = rp ^ 2048;
      *(unsigned short*)(hb + wp + wbh) = f2bf(h);
      pm = fmaxf(pm, h);
      if (++tm == 5){
          x2b[(b0 + row)*(TP*H1) + tp*H1 + cell] = f2bf(pm);  // async bf16 store
          pm = -1e30f; tm = 0; ++tp;
      }
      tq = tqn; vnext = vn2;
      rp = wp;
      bar_lds();
  }
}

// ---------------------------------------------------------------------------
// Kernel 2: layer-2 LSTM. 4 rows/block, 256 blocks, 8 waves; 26 tiles split
// 4,4,3,3,3,3,3,3. x enters as REGISTER B-fragments loaded directly from
// global bf16 x2 (prefetched 1 full step ahead) — no staging waves, no x in
// LDS, no barrier straggler. h (128-wide bf16, swizzled) ping-pongs in LDS.
// gl2 redistribute -> 1 update/lane; split accumulators.
// ---------------------------------------------------------------------------
__global__ __launch_bounds__(512, 1) void k_lstm2(
    const unsigned short* __restrict__ x2b, const float* __restrict__ Wih,
    const float* __restrict__ Whh, const float* __restrict__ bih,
    const float* __restrict__ bhh, const float* __restrict__ fcw,
    const float* __restrict__ fcb, float* __restrict__ out){
  __shared__ __align__(16) unsigned short blds[2][16*128];   // 8192 B (h only)
  __shared__ __align__(16) f32x4 gl2[108*4];                 // 6912 B [cell][row]
  __shared__ float fcred[8][4];

  const int tid = threadIdx.x;
  const int w = tid >> 6, l = tid & 63;
  const int b0 = blockIdx.x * 4;
  const int n = l & 15, kg = l >> 4;
  const int tlo = (w < 2) ? 4*w : 8 + 3*(w - 2);
  const int nt  = (w < 2) ? 4 : 3;

  { unsigned short* bz0 = (unsigned short*)blds;             // zero both h bufs
    for (int i = tid; i < 4096; i += 512) bz0[i] = 0; }
  { float* gz = (float*)gl2;
    for (int i = tid; i < 432*4; i += 512) gz[i] = 0.f; }

  // A fragments: [W_ih2 | W_hh2] permuted * LOG2E, zero-padded
  bf16x8 af[4][6];
  #pragma unroll
  for (int u = 0; u < 4; ++u){
      if (u < nt){
          const int p = 16*(tlo + u) + n;
          const int cell_ = p >> 2, gate = p & 3;
          #pragma unroll
          for (int c = 0; c < 6; ++c){
              bf16x8 f;
              #pragma unroll
              for (int jj = 0; jj < 8; ++jj){
                  int k = c*32 + kg*8 + jj;
                  float vv = 0.f;
                  if (cell_ < H2){
                      if (k < 64)           vv = Wih[(gate*H2 + cell_)*H1 + k];
                      else if (k < 64 + H2) vv = Whh[(gate*H2 + cell_)*H2 + (k - 64)];
                  }
                  f[jj] = (short)f2bf(vv * LOG2E);
              }
              af[u][c] = f;
          }
      }
  }

  // bias C-init quads (producer layout), * LOG2E
  f32x4 bz[4];
  #pragma unroll
  for (int u = 0; u < 4; ++u){
      const int cu = 4*(tlo + u) + kg;
      f32x4 b = {0.f,0.f,0.f,0.f};
      if (u < nt && cu < H2){
          #pragma unroll
          for (int g = 0; g < 4; ++g) b[g] = (bih[g*H2 + cu] + bhh[g*H2 + cu]) * LOG2E;
      }
      bz[u] = b;
  }

  // consumer: lane l -> cell = 4*tlo + (l>>2), row = l&3; active if in-range
  const bool act = (l >> 2) < 4*nt;
  const int cellc = 4*tlo + (l >> 2);
  const int r_c = l & 3;
  const float fwv = (act && cellc < H2) ? fcw[cellc] : 0.f;
  const float twoL = 2.0f * LOG2E;

  char* bb = (char*)blds;
  char* gb = (char*)gl2;
  // h-fragment reads: k = 64 + (j*32 + kg*8), j=0..3 -> h index j*32+kg*8
  int rbh[4];
  #pragma unroll
  for (int j = 0; j < 4; ++j)
      rbh[j] = (n*256 + 2*(j*32 + 8*kg)) ^ ((n & 7) << 4);
  const int wbh = (r_c*256 + 2*cellc) ^ ((r_c & 7) << 4);

  // x B-fragments straight from global (bf16), row-clamped for junk cols
  const int nr = n & 3;
  const unsigned short* xrow = x2b + (b0 + nr)*(TP*H1) + kg*8;
  bf16x8 x0 = *(const bf16x8*)(xrow);          // t=0, k=0..31 chunk
  bf16x8 x1 = *(const bf16x8*)(xrow + 32);     // t=0, k=32..63 chunk
  float cc = 0.f, hv = 0.f;
  __syncthreads();

  int rp = 0;
  for (int t = 0; t < TP; ++t){
      bf16x8 xn0, xn1;
      if (t + 1 < TP){                         // prefetch next step's x frags
          xn0 = *(const bf16x8*)(xrow + (t+1)*H1);
          xn1 = *(const bf16x8*)(xrow + (t+1)*H1 + 32);
      }
      bf16x8 h0 = *(const bf16x8*)(bb + rp + rbh[0]);
      bf16x8 h1 = *(const bf16x8*)(bb + rp + rbh[1]);
      bf16x8 h2 = *(const bf16x8*)(bb + rp + rbh[2]);
      bf16x8 h3 = *(const bf16x8*)(bb + rp + rbh[3]);
      #pragma unroll
      for (int u = 0; u < 4; ++u){
          if (u < nt){
              f32x4 za = __builtin_amdgcn_mfma_f32_16x16x32_bf16(af[u][0], x0, bz[u], 0,0,0);
              f32x4 zb = __builtin_amdgcn_mfma_f32_16x16x32_bf16(af[u][1], x1, (f32x4){0.f,0.f,0.f,0.f}, 0,0,0);
              za = __builtin_amdgcn_mfma_f32_16x16x32_bf16(af[u][2], h0, za, 0,0,0);
              zb = __builtin_amdgcn_mfma_f32_16x16x32_bf16(af[u][3], h1, zb, 0,0,0);
              za = __builtin_amdgcn_mfma_f32_16x16x32_bf16(af[u][4], h2, za, 0,0,0);
              zb = __builtin_amdgcn_mfma_f32_16x16x32_bf16(af[u][5], h3, zb, 0,0,0);
              f32x4 z = za + zb;
              if (n < 4)                        // cell 4*(tlo+u)+kg, row n
                  *(f32x4*)(gb + 256*(tlo + u) + 64*kg + 16*n) = z;
          }
      }
      wait_lds();
      const int wp = rp ^ 4096;
      if (act){
          f32x4 q = *(const f32x4*)(gb + 256*tlo + 16*l);
          float si = rcp(1.f + ex2(-q[0]));
          float sf = rcp(1.f + ex2(-q[1]));
          float so = rcp(1.f + ex2(-q[3]));
          float tg = 1.f - 2.f*rcp(1.f + ex2(q[2] + q[2]));
          cc = sf*cc + si*tg;
          float th = 1.f - 2.f*rcp(1.f + ex2(twoL*cc));
          hv = so*th;
          *(unsigned short*)(bb + wp + wbh) = f2bf(hv);  // k>=164 weights are 0
      }
      x0 = xn0; x1 = xn1;
      rp = wp;
      bar_lds();
  }

  // FC + sigmoid: p=0 on junk lanes, reduce cells then waves
  float p = (act && cellc < H2) ? hv * fwv : 0.f;
  p += __shfl_xor(p, 4);
  p += __shfl_xor(p, 8);
  p += __shfl_xor(p, 16);
  p += __shfl_xor(p, 32);
  if (l < 4) fcred[w][l] = p;
  __syncthreads();
  if (tid < 4){
      float s = 0.f;
      #pragma unroll
      for (int ww = 0; ww < 8; ++ww) s += fcred[ww][tid];
      s += fcb[0];
      out[b0 + tid] = rcp(1.f + ex2(-s * LOG2E));
  }
}

// ---------------------------------------------------------------------------
extern "C" void kernel_launch(void* const* d_in, const int* in_sizes, int n_in,
                              void* d_out, int out_size, void* d_ws, size_t ws_size,
                              hipStream_t stream) {
    const int*   x_idx = (const int*)  d_in[0];
    const float* emb   = (const float*)d_in[1];
    const float* Wih1  = (const float*)d_in[2];
    const float* Whh1  = (const float*)d_in[3];
    const float* bih1  = (const float*)d_in[4];
    const float* bhh1  = (const float*)d_in[5];
    const float* Wih2  = (const float*)d_in[6];
    const float* Whh2  = (const float*)d_in[7];
    const float* bih2  = (const float*)d_in[8];
    const float* bhh2  = (const float*)d_in[9];
    const float* fcw   = (const float*)d_in[10];
    const float* fcb   = (const float*)d_in[11];
    float* out = (float*)d_out;

    float*          table = (float*)d_ws;                    // 21840 B
    unsigned short* x2b   = (unsigned short*)((char*)d_ws + 32768); // 13.1 MB bf16

    k_table<<<VOCAB, 256, 0, stream>>>(Wih1, emb, bih1, bhh1, table);
    k_lstm1<<<NB / 16, 1024, 0, stream>>>(x_idx, Whh1, table, x2b);
    k_lstm2<<<NB / 4, 512, 0, stream>>>(x2b, Wih2, Whh2, bih2, bhh2, fcw, fcb, out);
}